// Round 9
// baseline (299.012 us; speedup 1.0000x reference)
//
#include <hip/hip_runtime.h>
#include <math.h>

#define N_PTS   1000000
#define CI      10
#define C       64
#define NSEG    30000
#define BN_EPS  1e-3f
#define FROFF   31104      // float index of fragment blob (after starts ints)

// ws layout (floats):
// [0:10)    colsum(inp)              (accumulator, zeroed)
// [10:65)   M = sum row*row^T, upper-tri i<=j row-major (55)  (zeroed)
// [256:320) g_sum                    (accumulator, zeroed)
// ints at [1024:31024): segment starts
// [FROFF : FROFF+15*256): per-lane fragment blob, 15 items x 64 lanes x 16B

using f32x4 = __attribute__((ext_vector_type(4))) float;
using s16x8 = __attribute__((ext_vector_type(8))) short;

__device__ inline short f2bf(float x) {           // RNE fp32 -> bf16 (weights)
    unsigned u = __float_as_uint(x);
    unsigned r = (u + 0x7fffu + ((u >> 16) & 1u)) >> 16;
    return (short)r;
}
__device__ inline unsigned pack_trunc(float lo, float hi) {  // 2x bf16 truncate
    return (__float_as_uint(hi) & 0xffff0000u) | (__float_as_uint(lo) >> 16);
}
__device__ inline float frcp(float x) { return __builtin_amdgcn_rcpf(x); }
// LDS-only drain: write->read visibility within a wave; does NOT touch vmcnt
// so global prefetch loads stay in flight. read->next-write anti-dep needs no
// fence (per-wave DS pipe is in-order).
__device__ inline void lds_fence() {
    asm volatile("s_waitcnt lgkmcnt(0)" ::: "memory");
}

struct Rows { float2 r0, r1, r2, r3; };

// Kernel 1: colsum[10] + second-moment M[55] of raw inputs (BN stats from 65
// scalars since linear commutes with the point-sum). Fused: segment starts.
__global__ void __launch_bounds__(256) k_moments(const float* __restrict__ inp,
                                                 const int* __restrict__ idx,
                                                 float* __restrict__ ws,
                                                 int* __restrict__ starts) {
    const int tid = threadIdx.x;
    float v[65];
#pragma unroll
    for (int k = 0; k < 65; ++k) v[k] = 0.f;

    for (int p = blockIdx.x * blockDim.x + tid; p < N_PTS; p += gridDim.x * blockDim.x) {
        const float2* r2 = (const float2*)(inp + (size_t)p * CI);
        float2 a0 = r2[0], a1 = r2[1], a2 = r2[2], a3 = r2[3], a4 = r2[4];
        float r[CI] = {a0.x, a0.y, a1.x, a1.y, a2.x, a2.y, a3.x, a3.y, a4.x, a4.y};
#pragma unroll
        for (int i = 0; i < CI; ++i) v[i] += r[i];
        int kk = 10;
#pragma unroll
        for (int i = 0; i < CI; ++i)
#pragma unroll
            for (int j = i; j < CI; ++j) { v[kk] = fmaf(r[i], r[j], v[kk]); ++kk; }

        int iv = idx[p];
        if (p == 0) starts[0] = 0;
        else if (idx[p - 1] != iv) starts[iv] = p;
    }

#pragma unroll
    for (int k = 0; k < 65; ++k) {
#pragma unroll
        for (int off = 32; off >= 1; off >>= 1)
            v[k] += __shfl_xor(v[k], off, 64);
    }
    __shared__ float red[4 * 65];
    const int wv = tid >> 6, ln = tid & 63;
    if (ln == 0) {
#pragma unroll
        for (int k = 0; k < 65; ++k) red[wv * 65 + k] = v[k];
    }
    __syncthreads();
    if (tid < 65)
        atomicAdd(&ws[tid], red[tid] + red[65 + tid] + red[130 + tid] + red[195 + tid]);
}

// Kernel 2 (fused finalize + gstats): per-block BN finalize from the 65
// moments (LDS only), then g_sum[c] = sum_p relu(x'_pc + b_c) via MFMA
// linear. 32 points per iteration (two independent 16-pt chains), 2-deep
// row prefetch.
__global__ void __launch_bounds__(256) k_gstats(const float* __restrict__ inp,
                                                const float* __restrict__ W,
                                                const float* __restrict__ gamma,
                                                const float* __restrict__ beta,
                                                float* __restrict__ ws) {
    const int tid  = threadIdx.x;
    const int wv   = tid >> 6;
    const int lane = tid & 63;
    const int m = lane & 15;
    const int q = lane >> 4;

    __shared__ float wp[C * CI];   // W' = a*W
    __shared__ float bsh[C];

    if (tid < C) {
        const int c = tid;
        float w[CI];
#pragma unroll
        for (int i = 0; i < CI; ++i) w[i] = W[c * CI + i];
        const float inv_n = 1.f / (float)N_PTS;

        float mu = 0.f;
#pragma unroll
        for (int i = 0; i < CI; ++i) mu = fmaf(w[i], ws[i], mu);
        mu *= inv_n;

        float ex2 = 0.f;
        int kk = 10;
#pragma unroll
        for (int i = 0; i < CI; ++i)
#pragma unroll
            for (int j = i; j < CI; ++j) {
                float mm = ws[kk];
                float t = w[i] * w[j] * mm;
                ex2 += (i == j) ? t : 2.f * t;
                ++kk;
            }
        ex2 *= inv_n;

        float var = ex2 - mu * mu;
        float rstd = rsqrtf(var + BN_EPS);
        float a = rstd * gamma[c];
        float b = beta[c] - mu * a;
        bsh[c] = b;
#pragma unroll
        for (int i = 0; i < CI; ++i) wp[c * CI + i] = a * w[i];
    }
    __syncthreads();

    s16x8 wfr[4];
#pragma unroll
    for (int nt = 0; nt < 4; ++nt) {
        s16x8 t;
#pragma unroll
        for (int j = 0; j < 8; ++j) {
            int k = 8 * q + j;
            t[j] = (k < CI) ? f2bf(wp[(nt * 16 + m) * CI + k]) : (short)0;
        }
        wfr[nt] = t;
    }
    float bb[4];
#pragma unroll
    for (int nt = 0; nt < 4; ++nt) bb[nt] = bsh[nt * 16 + m];

    const int wid = blockIdx.x * 4 + wv;
    const int nw  = gridDim.x * 4;
    const int NB2 = N_PTS / 32;          // 31250

    auto loadrows = [&](int pb) -> Rows {
        Rows R;
        R.r0 = R.r1 = R.r2 = R.r3 = make_float2(0.f, 0.f);
        const float* row = inp + (size_t)(pb + m) * CI;
        if (q == 0) {
            R.r0 = *(const float2*)(row);     R.r1 = *(const float2*)(row + 2);
            R.r2 = *(const float2*)(row + 4); R.r3 = *(const float2*)(row + 6);
        } else if (q == 1) {
            R.r0 = *(const float2*)(row + 8);
        }
        return R;
    };
    auto mkfrag = [&](const Rows& L) -> s16x8 {
        union { s16x8 v; unsigned u[4]; } t;
        t.v = s16x8{0, 0, 0, 0, 0, 0, 0, 0};
        if (q < 2) t.u[0] = pack_trunc(L.r0.x, L.r0.y);
        if (q == 0) {
            t.u[1] = pack_trunc(L.r1.x, L.r1.y);
            t.u[2] = pack_trunc(L.r2.x, L.r2.y);
            t.u[3] = pack_trunc(L.r3.x, L.r3.y);
        }
        return t.v;
    };

    float sm[4] = {0.f, 0.f, 0.f, 0.f};
    const f32x4 zero = {0.f, 0.f, 0.f, 0.f};

    Rows PA, PB;
    if (wid < NB2) { PA = loadrows(wid * 32); PB = loadrows(wid * 32 + 16); }
    for (int b = wid; b < NB2; b += nw) {
        Rows LA = PA, LB = PB;
        if (b + nw < NB2) { PA = loadrows((b + nw) * 32); PB = loadrows((b + nw) * 32 + 16); }

        s16x8 tA = mkfrag(LA), tB = mkfrag(LB);
        f32x4 xtA[4], xtB[4];
#pragma unroll
        for (int nt = 0; nt < 4; ++nt) {
            xtA[nt] = __builtin_amdgcn_mfma_f32_16x16x32_bf16(tA, wfr[nt], zero, 0, 0, 0);
            xtB[nt] = __builtin_amdgcn_mfma_f32_16x16x32_bf16(tB, wfr[nt], zero, 0, 0, 0);
        }
#pragma unroll
        for (int nt = 0; nt < 4; ++nt)
#pragma unroll
            for (int r = 0; r < 4; ++r)
                sm[nt] += fmaxf(xtA[nt][r] + bb[nt], 0.f) + fmaxf(xtB[nt][r] + bb[nt], 0.f);
    }

#pragma unroll
    for (int nt = 0; nt < 4; ++nt) {
        sm[nt] += __shfl_xor(sm[nt], 16, 64);
        sm[nt] += __shfl_xor(sm[nt], 32, 64);
    }
    float S = sm[0];
    if (q == 1) S = sm[1];
    if (q == 2) S = sm[2];
    if (q == 3) S = sm[3];

    __shared__ float red[4 * 64];
    red[wv * 64 + lane] = S;              // lane == channel
    __syncthreads();
    if (tid < 64)
        atomicAdd(&ws[256 + tid], red[tid] + red[64 + tid] + red[128 + tid] + red[192 + tid]);
}

// Kernel 3: k_prep — BN finalize (lane = channel), fp32 xg, and all per-lane
// fragments for k_main, stored as [item][lane] 16B records.
// items 0..3: wfr[nt]; 4..11: bfr[nt][kc] (idx 4+2nt+kc); 12: bb; 13: d1v; 14: xgv
__global__ void k_prep(const float* __restrict__ W,
                       const float* __restrict__ gamma,
                       const float* __restrict__ beta,
                       const float* __restrict__ dw1,
                       const float* __restrict__ pw1,
                       const float* __restrict__ dw2,
                       const float* __restrict__ pw2,
                       float* __restrict__ ws) {
    const int lane = threadIdx.x;     // 0..63 ; lane == channel c
    const int m = lane & 15, q = lane >> 4;
    const float inv_n = 1.f / (float)N_PTS;

    __shared__ float WP[C * CI];   // W' = a*W
    __shared__ float BSH[C], T[C], XG[C];

    // ---- BN finalize for channel `lane`
    {
        float w[CI];
#pragma unroll
        for (int i = 0; i < CI; ++i) w[i] = W[lane * CI + i];
        float mu = 0.f;
#pragma unroll
        for (int i = 0; i < CI; ++i) mu = fmaf(w[i], ws[i], mu);
        mu *= inv_n;
        float ex2 = 0.f;
        int kk = 10;
#pragma unroll
        for (int i = 0; i < CI; ++i)
#pragma unroll
            for (int j = i; j < CI; ++j) {
                float mm = ws[kk];
                float t = w[i] * w[j] * mm;
                ex2 += (i == j) ? t : 2.f * t;
                ++kk;
            }
        ex2 *= inv_n;
        float var = ex2 - mu * mu;
        float rstd = rsqrtf(var + BN_EPS);
        float a = rstd * gamma[lane];
        BSH[lane] = beta[lane] - mu * a;
#pragma unroll
        for (int i = 0; i < CI; ++i) WP[lane * CI + i] = a * w[i];
        T[lane] = fmaxf(dw2[lane] * (ws[256 + lane] * inv_n), 0.f);
    }
    __syncthreads();

    // ---- xg = pw2 @ relu(dw2*g)  (exact fp32)
    {
        float acc = 0.f;
#pragma unroll
        for (int k = 0; k < C; ++k) acc = fmaf(pw2[lane * C + k], T[k], acc);
        XG[lane] = acc;
    }
    __syncthreads();

    float4* FR = (float4*)(ws + FROFF);
    union { float4 f; s16x8 v; } u;

#pragma unroll
    for (int nt = 0; nt < 4; ++nt) {
        s16x8 tt;
#pragma unroll
        for (int j = 0; j < 8; ++j) {
            int k = 8 * q + j;
            tt[j] = (k < CI) ? f2bf(WP[(nt * 16 + m) * CI + k]) : (short)0;
        }
        u.v = tt; FR[nt * 64 + lane] = u.f;
    }
#pragma unroll
    for (int nt = 0; nt < 4; ++nt)
#pragma unroll
        for (int kc = 0; kc < 2; ++kc) {
            const float* src = pw1 + (nt * 16 + m) * C + kc * 32 + q * 8;
            float4 p0 = *(const float4*)src, p1 = *(const float4*)(src + 4);
            s16x8 tt;
            tt[0] = f2bf(p0.x); tt[1] = f2bf(p0.y); tt[2] = f2bf(p0.z); tt[3] = f2bf(p0.w);
            tt[4] = f2bf(p1.x); tt[5] = f2bf(p1.y); tt[6] = f2bf(p1.z); tt[7] = f2bf(p1.w);
            u.v = tt; FR[(4 + nt * 2 + kc) * 64 + lane] = u.f;
        }
    float4 f;
    f.x = BSH[m]; f.y = BSH[16 + m]; f.z = BSH[32 + m]; f.w = BSH[48 + m];
    FR[12 * 64 + lane] = f;
    f.x = dw1[m]; f.y = dw1[16 + m]; f.z = dw1[32 + m]; f.w = dw1[48 + m];
    FR[13 * 64 + lane] = f;
    f.x = XG[m]; f.y = XG[16 + m]; f.z = XG[32 + m]; f.w = XG[48 + m];
    FR[14 * 64 + lane] = f;
}

// Kernel 4: k_main — one wave per 2 contiguous segments; 32 points per
// iteration as TWO independent 16-pt sub-batches (ILP: the compiler overlaps
// A's VALU/trans phase with B's MFMA phase). One lgkmcnt fence per 32 pts.
// 1-iteration (32-pt) row prefetch; segmented sum/max per sub-batch.
#define LD 68
#define SEGW 2
__global__ void __launch_bounds__(128) k_main(const float* __restrict__ inp,
                                              const float* __restrict__ ws,
                                              const int* __restrict__ starts,
                                              float* __restrict__ out) {
    const int tid  = threadIdx.x;
    const int wv   = tid >> 6;
    const int lane = tid & 63;
    const int m = lane & 15;
    const int q = lane >> 4;
    const f32x4 zero = {0.f, 0.f, 0.f, 0.f};

    const float4* FR = (const float4*)(ws + FROFF);
    union { float4 f; s16x8 v; } u;
    s16x8 wfr[4];
#pragma unroll
    for (int nt = 0; nt < 4; ++nt) { u.f = FR[nt * 64 + lane]; wfr[nt] = u.v; }
    s16x8 bfr[4][2];
#pragma unroll
    for (int nt = 0; nt < 4; ++nt)
#pragma unroll
        for (int kc = 0; kc < 2; ++kc) { u.f = FR[(4 + nt * 2 + kc) * 64 + lane]; bfr[nt][kc] = u.v; }
    const float4 bb4  = FR[12 * 64 + lane];
    const float4 d14  = FR[13 * 64 + lane];
    const float4 xg4  = FR[14 * 64 + lane];
    const float bb[4]  = {bb4.x, bb4.y, bb4.z, bb4.w};
    const float d1v[4] = {d14.x, d14.y, d14.z, d14.w};
    const float xgv[4] = {xg4.x, xg4.y, xg4.z, xg4.w};

    __shared__ float sb[2][32 * LD];
    float* my = sb[wv];

    const int w  = blockIdx.x * 2 + wv;    // 0..14999
    const int s0 = w * SEGW;

    int st1 = starts[s0 + 1];
    int st2 = (s0 + 2 < NSEG) ? starts[s0 + 2] : N_PTS;
    const int start   = starts[s0];
    const int end_all = st2;

    int cur = s0;
    int end_cur = st1;

    float sm[4]  = {0.f, 0.f, 0.f, 0.f};
    float mxv[4] = {-INFINITY, -INFINITY, -INFINITY, -INFINITY};

    auto flushseg = [&](int s) {
#pragma unroll
        for (int nt = 0; nt < 4; ++nt) {
            sm[nt] += __shfl_xor(sm[nt], 16, 64);
            sm[nt] += __shfl_xor(sm[nt], 32, 64);
            mxv[nt] = fmaxf(mxv[nt], __shfl_xor(mxv[nt], 16, 64));
            mxv[nt] = fmaxf(mxv[nt], __shfl_xor(mxv[nt], 32, 64));
        }
        float S = sm[0], M = mxv[0];
        if (q == 1) { S = sm[1]; M = mxv[1]; }
        if (q == 2) { S = sm[2]; M = mxv[2]; }
        if (q == 3) { S = sm[3]; M = mxv[3]; }
        out[(size_t)s * C + lane] = S + M;
#pragma unroll
        for (int nt = 0; nt < 4; ++nt) { sm[nt] = 0.f; mxv[nt] = -INFINITY; }
    };

    // segmented accumulate for one 16-pt sub-batch at bbase with nb valid pts
    auto accum = [&](f32x4 (&xi)[4], int bbase, int nb) {
        const int fin = bbase + nb;
        if (fin <= end_cur) {
            if (nb == 16) {
#pragma unroll
                for (int nt = 0; nt < 4; ++nt)
#pragma unroll
                    for (int r = 0; r < 4; ++r) {
                        sm[nt] += xi[nt][r];
                        mxv[nt] = fmaxf(mxv[nt], xi[nt][r]);
                    }
            } else {
#pragma unroll
                for (int nt = 0; nt < 4; ++nt)
#pragma unroll
                    for (int r = 0; r < 4; ++r) {
                        bool act = (4 * q + r) < nb;
                        sm[nt] += act ? xi[nt][r] : 0.f;
                        mxv[nt] = fmaxf(mxv[nt], act ? xi[nt][r] : -INFINITY);
                    }
            }
            if (fin == end_cur) { flushseg(cur); ++cur; end_cur = st2; }
        } else {
            const int B = end_cur - bbase;   // 1..nb-1 (boundary strictly inside)
#pragma unroll
            for (int nt = 0; nt < 4; ++nt)
#pragma unroll
                for (int r = 0; r < 4; ++r) {
                    bool act = (4 * q + r) < B;
                    sm[nt] += act ? xi[nt][r] : 0.f;
                    mxv[nt] = fmaxf(mxv[nt], act ? xi[nt][r] : -INFINITY);
                }
            flushseg(cur); ++cur;
#pragma unroll
            for (int nt = 0; nt < 4; ++nt)
#pragma unroll
                for (int r = 0; r < 4; ++r) {
                    int pt = 4 * q + r;
                    bool act = (pt >= B) && (pt < nb);
                    sm[nt] += act ? xi[nt][r] : 0.f;
                    mxv[nt] = fmaxf(mxv[nt], act ? xi[nt][r] : -INFINITY);
                }
            end_cur = st2;
        }
    };

    auto loadrows = [&](int pb) -> Rows {
        Rows R;
        R.r0 = R.r1 = R.r2 = R.r3 = make_float2(0.f, 0.f);
        const float* row = inp + (size_t)min(pb + m, N_PTS - 1) * CI;
        if (q == 0) {
            R.r0 = *(const float2*)(row);     R.r1 = *(const float2*)(row + 2);
            R.r2 = *(const float2*)(row + 4); R.r3 = *(const float2*)(row + 6);
        } else if (q == 1) {
            R.r0 = *(const float2*)(row + 8);
        }
        return R;
    };
    auto mkfrag = [&](const Rows& L) -> s16x8 {
        union { s16x8 v; unsigned u[4]; } t;
        t.v = s16x8{0, 0, 0, 0, 0, 0, 0, 0};
        if (q < 2) t.u[0] = pack_trunc(L.r0.x, L.r0.y);
        if (q == 0) {
            t.u[1] = pack_trunc(L.r1.x, L.r1.y);
            t.u[2] = pack_trunc(L.r2.x, L.r2.y);
            t.u[3] = pack_trunc(L.r3.x, L.r3.y);
        }
        return t.v;
    };

    Rows PA = loadrows(start);
    Rows PB = loadrows(start + 16);      // clamped load; masked out if past end

    for (int base = start; base < end_all; base += 32) {
        Rows LA = PA, LB = PB;
        if (base + 32 < end_all) { PA = loadrows(base + 32); PB = loadrows(base + 48); }

        const int nbA = min(16, end_all - base);
        const int nbB = min(16, max(0, end_all - base - 16));

        // ---- A-frags + linear MFMA for both sub-batches (independent)
        s16x8 tA = mkfrag(LA), tB = mkfrag(LB);
        f32x4 xtA[4], xtB[4];
#pragma unroll
        for (int nt = 0; nt < 4; ++nt) {
            xtA[nt] = __builtin_amdgcn_mfma_f32_16x16x32_bf16(tA, wfr[nt], zero, 0, 0, 0);
            xtB[nt] = __builtin_amdgcn_mfma_f32_16x16x32_bf16(tB, wfr[nt], zero, 0, 0, 0);
        }

        // ---- BN + ReLU + swish; sw -> LDS rows [0:16) for A, [16:32) for B
        float xnA[4][4], xnB[4][4];
#pragma unroll
        for (int nt = 0; nt < 4; ++nt)
#pragma unroll
            for (int r = 0; r < 4; ++r) {
                float xa = fmaxf(xtA[nt][r] + bb[nt], 0.f);
                float xb = fmaxf(xtB[nt][r] + bb[nt], 0.f);
                xnA[nt][r] = xa; xnB[nt][r] = xb;
                float sa = xa * d1v[nt], sbv = xb * d1v[nt];
                float swa = sa * frcp(1.f + __expf(-sa));
                float swb = sbv * frcp(1.f + __expf(-sbv));
                my[(4 * q + r) * LD + nt * 16 + m] = swa;
                my[(16 + 4 * q + r) * LD + nt * 16 + m] = swb;
            }
        lds_fence();

        // ---- A-frags of sw for second MFMA
        s16x8 avA[2], avB[2];
#pragma unroll
        for (int kc = 0; kc < 2; ++kc) {
            const float* srcA = &my[m * LD + kc * 32 + q * 8];
            const float* srcB = &my[(16 + m) * LD + kc * 32 + q * 8];
            float4 a0 = *(const float4*)srcA, a1 = *(const float4*)(srcA + 4);
            float4 b0 = *(const float4*)srcB, b1 = *(const float4*)(srcB + 4);
            union { s16x8 v; unsigned u[4]; } ta, tb;
            ta.u[0] = pack_trunc(a0.x, a0.y); ta.u[1] = pack_trunc(a0.z, a0.w);
            ta.u[2] = pack_trunc(a1.x, a1.y); ta.u[3] = pack_trunc(a1.z, a1.w);
            tb.u[0] = pack_trunc(b0.x, b0.y); tb.u[1] = pack_trunc(b0.z, b0.w);
            tb.u[2] = pack_trunc(b1.x, b1.y); tb.u[3] = pack_trunc(b1.z, b1.w);
            avA[kc] = ta.v; avB[kc] = tb.v;
        }

        // ---- xl = sw @ pw1^T (C-layout, aligned with xn)
        f32x4 xiA[4], xiB[4];
#pragma unroll
        for (int nt = 0; nt < 4; ++nt) {
            xiA[nt] = __builtin_amdgcn_mfma_f32_16x16x32_bf16(avA[0], bfr[nt][0], zero, 0, 0, 0);
            xiA[nt] = __builtin_amdgcn_mfma_f32_16x16x32_bf16(avA[1], bfr[nt][1], xiA[nt], 0, 0, 0);
            xiB[nt] = __builtin_amdgcn_mfma_f32_16x16x32_bf16(avB[0], bfr[nt][0], zero, 0, 0, 0);
            xiB[nt] = __builtin_amdgcn_mfma_f32_16x16x32_bf16(avB[1], bfr[nt][1], xiB[nt], 0, 0, 0);
        }
        // no fence: per-wave DS pipe is in-order (next iter's writes cannot
        // bypass this iter's reads)

        // ---- epilogue in registers
#pragma unroll
        for (int nt = 0; nt < 4; ++nt)
#pragma unroll
            for (int r = 0; r < 4; ++r) {
                float va = xiA[nt][r] + xgv[nt];
                float vb = xiB[nt][r] + xgv[nt];
                float wa = frcp(1.f + __expf(-va));
                float wb = frcp(1.f + __expf(-vb));
                xiA[nt][r] = fmaf(xnA[nt][r], wa, xnA[nt][r]);
                xiB[nt][r] = fmaf(xnB[nt][r], wb, xnB[nt][r]);
            }

        // ---- segmented accumulate, sub-batch A then B
        accum(xiA, base, nbA);
        if (nbB > 0) accum(xiB, base + 16, nbB);
    }
}

extern "C" void kernel_launch(void* const* d_in, const int* in_sizes, int n_in,
                              void* d_out, int out_size, void* d_ws, size_t ws_size,
                              hipStream_t stream) {
    const float* inp   = (const float*)d_in[0];
    const int*   unq   = (const int*)d_in[1];
    const float* W     = (const float*)d_in[2];
    const float* gamma = (const float*)d_in[3];
    const float* beta  = (const float*)d_in[4];
    const float* dw1   = (const float*)d_in[5];
    const float* pw1   = (const float*)d_in[6];
    const float* dw2   = (const float*)d_in[7];
    const float* pw2   = (const float*)d_in[8];
    float* out = (float*)d_out;
    float* ws  = (float*)d_ws;
    int* starts = (int*)ws + 1024;

    hipMemsetAsync(ws, 0, 384 * sizeof(float), stream);   // zero accumulators

    k_moments <<<1024, 256, 0, stream>>>(inp, unq, ws, starts);
    k_gstats  <<<2048, 256, 0, stream>>>(inp, W, gamma, beta, ws);
    k_prep    <<<1,    64,  0, stream>>>(W, gamma, beta, dw1, pw1, dw2, pw2, ws);
    k_main    <<<7500, 128, 0, stream>>>(inp, ws, starts, out);
}

// Round 11
// 294.794 us; speedup vs baseline: 1.0143x; 1.0143x over previous
//
#include <hip/hip_runtime.h>
#include <math.h>

#define N_PTS   1000000
#define CI      10
#define C       64
#define NSEG    30000
#define BN_EPS  1e-3f

#define NBLK_M  2048
#define NBLK_G  2048
#define P1STR   72
#define P1OFF   32768                         // after starts ints
#define P2OFF   (P1OFF + NBLK_M * P1STR)      // 180224
#define FROFF   (P2OFF + NBLK_G * 64)         // 311296  (~1.26 MB ws total)

// ws layout (floats):
// [0:65)    reduced moments (colsum[10] + M upper-tri[55]) — written by k_red
// ints at [1024:31024): segment starts (fully overwritten every launch)
// [P1OFF:)  k_moments per-block partials, 65 used of stride 72
// [P2OFF:)  k_gstats per-block partials, 64 per block
// [FROFF:)  per-lane fragment blob, 15 items x 64 lanes x 16B
// NO accumulators -> no memset node, no global atomics anywhere.

using f32x4 = __attribute__((ext_vector_type(4))) float;
using s16x8 = __attribute__((ext_vector_type(8))) short;

__device__ inline short f2bf(float x) {           // RNE fp32 -> bf16 (weights)
    unsigned u = __float_as_uint(x);
    unsigned r = (u + 0x7fffu + ((u >> 16) & 1u)) >> 16;
    return (short)r;
}
__device__ inline unsigned pack_trunc(float lo, float hi) {  // 2x bf16 truncate
    return (__float_as_uint(hi) & 0xffff0000u) | (__float_as_uint(lo) >> 16);
}
__device__ inline float frcp(float x) { return __builtin_amdgcn_rcpf(x); }
// LDS-only drain: write->read visibility within a wave; does NOT touch vmcnt
// so global prefetch loads stay in flight (the R7->R8 win).
__device__ inline void lds_fence() {
    asm volatile("s_waitcnt lgkmcnt(0)" ::: "memory");
}

struct Rows { float2 r0, r1, r2, r3; };
__device__ inline Rows zrows() {
    Rows R; R.r0 = R.r1 = R.r2 = R.r3 = make_float2(0.f, 0.f); return R;
}

// Kernel 1: moments via PAIR loads (2 rows = 80 B = 5 aligned float4s; half
// the load instrs of float2-per-row). 2048x256: every thread <=1 pair -> all
// loads independent/in-flight. Block partials to DISTINCT addresses.
__global__ void __launch_bounds__(256) k_moments(const float* __restrict__ inp,
                                                 const int* __restrict__ idx,
                                                 float* __restrict__ ws,
                                                 int* __restrict__ starts) {
    const int tid = threadIdx.x;
    float v[65];
#pragma unroll
    for (int k = 0; k < 65; ++k) v[k] = 0.f;

    const int NPP = N_PTS / 2;   // 500000 pairs
    for (int pp = blockIdx.x * blockDim.x + tid; pp < NPP; pp += gridDim.x * blockDim.x) {
        const float4* base = (const float4*)(inp + (size_t)pp * 20);
        float4 a = base[0], b4 = base[1], c = base[2], d = base[3], e = base[4];
        float r0[CI] = {a.x, a.y, a.z, a.w, b4.x, b4.y, b4.z, b4.w, c.x, c.y};
        float r1[CI] = {c.z, c.w, d.x, d.y, d.z, d.w, e.x, e.y, e.z, e.w};
#pragma unroll
        for (int i = 0; i < CI; ++i) v[i] += r0[i] + r1[i];
        int kk = 10;
#pragma unroll
        for (int i = 0; i < CI; ++i)
#pragma unroll
            for (int j = i; j < CI; ++j) {
                v[kk] = fmaf(r0[i], r0[j], v[kk]);
                v[kk] = fmaf(r1[i], r1[j], v[kk]);
                ++kk;
            }

        // segment starts: p0=2pp (checked vs idx[p0-1]), p1=2pp+1
        const int p0 = 2 * pp;
        int2 iv = *(const int2*)(idx + p0);
        if (p0 == 0) starts[0] = 0;
        else { int prev = idx[p0 - 1]; if (prev != iv.x) starts[iv.x] = p0; }
        if (iv.x != iv.y) starts[iv.y] = p0 + 1;
    }

#pragma unroll
    for (int k = 0; k < 65; ++k) {
#pragma unroll
        for (int off = 32; off >= 1; off >>= 1)
            v[k] += __shfl_xor(v[k], off, 64);
    }
    __shared__ float red[4 * 65];
    const int wv = tid >> 6, ln = tid & 63;
    if (ln == 0) {
#pragma unroll
        for (int k = 0; k < 65; ++k) red[wv * 65 + k] = v[k];
    }
    __syncthreads();
    if (tid < 65)
        ws[P1OFF + blockIdx.x * P1STR + tid] =
            red[tid] + red[65 + tid] + red[130 + tid] + red[195 + tid];
}

// Kernel 2: reduce moments partials. Block k sums P1[b][k] over 2048 blocks.
__global__ void __launch_bounds__(256) k_red(float* __restrict__ ws) {
    const int k = blockIdx.x;            // 0..64
    float s = 0.f;
    for (int i = threadIdx.x; i < NBLK_M; i += 256)
        s += ws[P1OFF + i * P1STR + k];
    __shared__ float r[256];
    r[threadIdx.x] = s;
    __syncthreads();
#pragma unroll
    for (int off = 128; off > 0; off >>= 1) {
        if (threadIdx.x < off) r[threadIdx.x] += r[threadIdx.x + off];
        __syncthreads();
    }
    if (threadIdx.x == 0) ws[k] = r[0];
}

// Kernel 3: gstats — per-block BN finalize (LDS only) from reduced moments,
// then g partial[c] = sum_p relu(x'_pc + b_c) via MFMA linear. 8192 waves,
// ~7.6 batches each, 2-deep row prefetch. Partials to distinct addresses.
__global__ void __launch_bounds__(256) k_gstats(const float* __restrict__ inp,
                                                const float* __restrict__ W,
                                                const float* __restrict__ gamma,
                                                const float* __restrict__ beta,
                                                float* __restrict__ ws) {
    const int tid  = threadIdx.x;
    const int wv   = tid >> 6;
    const int lane = tid & 63;
    const int m = lane & 15;
    const int q = lane >> 4;
    const float inv_n = 1.f / (float)N_PTS;

    __shared__ float wp[C * CI];   // W' = a*W
    __shared__ float bsh[C];

    if (tid < C) {
        const int c = tid;
        float w[CI];
#pragma unroll
        for (int i = 0; i < CI; ++i) w[i] = W[c * CI + i];
        float mu = 0.f;
#pragma unroll
        for (int i = 0; i < CI; ++i) mu = fmaf(w[i], ws[i], mu);
        mu *= inv_n;
        float ex2 = 0.f;
        int kk = 10;
#pragma unroll
        for (int i = 0; i < CI; ++i)
#pragma unroll
            for (int j = i; j < CI; ++j) {
                float mm = ws[kk];
                float t = w[i] * w[j] * mm;
                ex2 += (i == j) ? t : 2.f * t;
                ++kk;
            }
        ex2 *= inv_n;
        float var = ex2 - mu * mu;
        float rstd = rsqrtf(var + BN_EPS);
        float a = rstd * gamma[c];
        bsh[c] = beta[c] - mu * a;
#pragma unroll
        for (int i = 0; i < CI; ++i) wp[c * CI + i] = a * w[i];
    }
    __syncthreads();

    s16x8 wfr[4];
#pragma unroll
    for (int nt = 0; nt < 4; ++nt) {
        s16x8 t;
#pragma unroll
        for (int j = 0; j < 8; ++j) {
            int k = 8 * q + j;
            t[j] = (k < CI) ? f2bf(wp[(nt * 16 + m) * CI + k]) : (short)0;
        }
        wfr[nt] = t;
    }
    float bb[4];
#pragma unroll
    for (int nt = 0; nt < 4; ++nt) bb[nt] = bsh[nt * 16 + m];

    auto loadrows = [&](int pb) -> Rows {
        Rows R = zrows();
        const float* row = inp + (size_t)(pb + m) * CI;
        if (q == 0) {
            R.r0 = *(const float2*)(row);     R.r1 = *(const float2*)(row + 2);
            R.r2 = *(const float2*)(row + 4); R.r3 = *(const float2*)(row + 6);
        } else if (q == 1) {
            R.r0 = *(const float2*)(row + 8);
        }
        return R;
    };
    auto mkfrag = [&](const Rows& L) -> s16x8 {
        union { s16x8 v; unsigned u[4]; } t;
        t.v = s16x8{0, 0, 0, 0, 0, 0, 0, 0};
        if (q < 2) t.u[0] = pack_trunc(L.r0.x, L.r0.y);
        if (q == 0) {
            t.u[1] = pack_trunc(L.r1.x, L.r1.y);
            t.u[2] = pack_trunc(L.r2.x, L.r2.y);
            t.u[3] = pack_trunc(L.r3.x, L.r3.y);
        }
        return t.v;
    };

    const int wid = blockIdx.x * 4 + wv;   // 0..8191
    const int STR = NBLK_G * 4;            // 8192
    const int NB  = N_PTS / 16;            // 62500

    float sm[4] = {0.f, 0.f, 0.f, 0.f};
    const f32x4 zero = {0.f, 0.f, 0.f, 0.f};

    Rows Pf0 = zrows(), Pf1 = zrows();
    if (wid < NB) Pf0 = loadrows(wid * 16);
    if (wid + STR < NB) Pf1 = loadrows((wid + STR) * 16);
    int j = 0;
    for (int i = wid; i < NB; i += STR, ++j) {
        Rows L = (j & 1) ? Pf1 : Pf0;
        if (i + 2 * STR < NB) {
            if (j & 1) Pf1 = loadrows((i + 2 * STR) * 16);
            else       Pf0 = loadrows((i + 2 * STR) * 16);
        }
        s16x8 t = mkfrag(L);
#pragma unroll
        for (int nt = 0; nt < 4; ++nt) {
            f32x4 xt = __builtin_amdgcn_mfma_f32_16x16x32_bf16(t, wfr[nt], zero, 0, 0, 0);
#pragma unroll
            for (int r = 0; r < 4; ++r)
                sm[nt] += fmaxf(xt[r] + bb[nt], 0.f);
        }
    }

#pragma unroll
    for (int nt = 0; nt < 4; ++nt) {
        sm[nt] += __shfl_xor(sm[nt], 16, 64);
        sm[nt] += __shfl_xor(sm[nt], 32, 64);
    }
    float S = sm[0];
    if (q == 1) S = sm[1];
    if (q == 2) S = sm[2];
    if (q == 3) S = sm[3];

    __shared__ float red[4 * 64];
    red[wv * 64 + lane] = S;              // lane == channel
    __syncthreads();
    if (tid < 64)
        ws[P2OFF + blockIdx.x * 64 + tid] =
            red[tid] + red[64 + tid] + red[128 + tid] + red[192 + tid];
}

// Kernel 4: k_prep — reduce gstats partials (1024 thr, 16 groups/channel),
// BN finalize, exact fp32 xg, and the per-lane fragment blob for k_main.
// items 0..3: wfr[nt]; 4..11: bfr[nt][kc] (4+2nt+kc); 12: bb; 13: d1v; 14: xgv
__global__ void __launch_bounds__(1024) k_prep(const float* __restrict__ W,
                                               const float* __restrict__ gamma,
                                               const float* __restrict__ beta,
                                               const float* __restrict__ dw1,
                                               const float* __restrict__ pw1,
                                               const float* __restrict__ dw2,
                                               const float* __restrict__ pw2,
                                               float* __restrict__ ws) {
    const int tid = threadIdx.x;
    const int c = tid & 63, g = tid >> 6;     // 16 groups x 64 channels
    const float inv_n = 1.f / (float)N_PTS;

    __shared__ float R[1024];
    __shared__ float GS[C], WP[C * CI], BSH[C], T[C], XG[C];

    // ---- reduce g_sum partials
    {
        float s = 0.f;
        for (int i = g; i < NBLK_G; i += 16)
            s += ws[P2OFF + i * 64 + c];
        R[tid] = s;
    }
    __syncthreads();
    if (g == 0) {
        float t = 0.f;
#pragma unroll
        for (int gg = 0; gg < 16; ++gg) t += R[gg * 64 + c];
        GS[c] = t;
    }
    __syncthreads();

    if (tid < C) {
        // ---- BN finalize for channel tid
        float w[CI];
#pragma unroll
        for (int i = 0; i < CI; ++i) w[i] = W[tid * CI + i];
        float mu = 0.f;
#pragma unroll
        for (int i = 0; i < CI; ++i) mu = fmaf(w[i], ws[i], mu);
        mu *= inv_n;
        float ex2 = 0.f;
        int kk = 10;
#pragma unroll
        for (int i = 0; i < CI; ++i)
#pragma unroll
            for (int j = i; j < CI; ++j) {
                float mm = ws[kk];
                float t = w[i] * w[j] * mm;
                ex2 += (i == j) ? t : 2.f * t;
                ++kk;
            }
        ex2 *= inv_n;
        float var = ex2 - mu * mu;
        float rstd = rsqrtf(var + BN_EPS);
        float a = rstd * gamma[tid];
        BSH[tid] = beta[tid] - mu * a;
#pragma unroll
        for (int i = 0; i < CI; ++i) WP[tid * CI + i] = a * w[i];
        T[tid] = fmaxf(dw2[tid] * (GS[tid] * inv_n), 0.f);
    }
    __syncthreads();

    if (tid < C) {
        float acc = 0.f;
#pragma unroll
        for (int k = 0; k < C; ++k) acc = fmaf(pw2[tid * C + k], T[k], acc);
        XG[tid] = acc;
    }
    __syncthreads();

    if (tid < C) {
        const int lane = tid, m = lane & 15, q = lane >> 4;
        float4* FR = (float4*)(ws + FROFF);
        union { float4 f; s16x8 v; } u;
#pragma unroll
        for (int nt = 0; nt < 4; ++nt) {
            s16x8 tt;
#pragma unroll
            for (int j = 0; j < 8; ++j) {
                int k = 8 * q + j;
                tt[j] = (k < CI) ? f2bf(WP[(nt * 16 + m) * CI + k]) : (short)0;
            }
            u.v = tt; FR[nt * 64 + lane] = u.f;
        }
#pragma unroll
        for (int nt = 0; nt < 4; ++nt)
#pragma unroll
            for (int kc = 0; kc < 2; ++kc) {
                const float* src = pw1 + (nt * 16 + m) * C + kc * 32 + q * 8;
                float4 p0 = *(const float4*)src, p1 = *(const float4*)(src + 4);
                s16x8 tt;
                tt[0] = f2bf(p0.x); tt[1] = f2bf(p0.y); tt[2] = f2bf(p0.z); tt[3] = f2bf(p0.w);
                tt[4] = f2bf(p1.x); tt[5] = f2bf(p1.y); tt[6] = f2bf(p1.z); tt[7] = f2bf(p1.w);
                u.v = tt; FR[(4 + nt * 2 + kc) * 64 + lane] = u.f;
            }
        float4 f;
        f.x = BSH[m]; f.y = BSH[16 + m]; f.z = BSH[32 + m]; f.w = BSH[48 + m];
        FR[12 * 64 + lane] = f;
        f.x = dw1[m]; f.y = dw1[16 + m]; f.z = dw1[32 + m]; f.w = dw1[48 + m];
        FR[13 * 64 + lane] = f;
        f.x = XG[m]; f.y = XG[16 + m]; f.z = XG[32 + m]; f.w = XG[48 + m];
        FR[14 * 64 + lane] = f;
    }
}

// Kernel 5: k_main — EXACT R8 body (best measured: 89 us). One wave per 2
// contiguous segments, 16-pt batches streamed across the boundary, segmented
// sum/max, row prefetch, LDS-only fences.
#define LD 68
#define SEGW 2
__global__ void __launch_bounds__(128) k_main(const float* __restrict__ inp,
                                              const float* __restrict__ ws,
                                              const int* __restrict__ starts,
                                              float* __restrict__ out) {
    const int tid  = threadIdx.x;
    const int wv   = tid >> 6;
    const int lane = tid & 63;
    const int m = lane & 15;
    const int q = lane >> 4;
    const f32x4 zero = {0.f, 0.f, 0.f, 0.f};

    const float4* FR = (const float4*)(ws + FROFF);
    union { float4 f; s16x8 v; } u;
    s16x8 wfr[4];
#pragma unroll
    for (int nt = 0; nt < 4; ++nt) { u.f = FR[nt * 64 + lane]; wfr[nt] = u.v; }
    s16x8 bfr[4][2];
#pragma unroll
    for (int nt = 0; nt < 4; ++nt)
#pragma unroll
        for (int kc = 0; kc < 2; ++kc) { u.f = FR[(4 + nt * 2 + kc) * 64 + lane]; bfr[nt][kc] = u.v; }
    const float4 bb4  = FR[12 * 64 + lane];
    const float4 d14  = FR[13 * 64 + lane];
    const float4 xg4  = FR[14 * 64 + lane];
    const float bb[4]  = {bb4.x, bb4.y, bb4.z, bb4.w};
    const float d1v[4] = {d14.x, d14.y, d14.z, d14.w};
    const float xgv[4] = {xg4.x, xg4.y, xg4.z, xg4.w};

    __shared__ float sb[2][16 * LD];
    float* my = sb[wv];

    const int w  = blockIdx.x * 2 + wv;    // 0..14999
    const int s0 = w * SEGW;

    int st1 = starts[s0 + 1];
    int st2 = (s0 + 2 < NSEG) ? starts[s0 + 2] : N_PTS;
    const int start   = starts[s0];
    const int end_all = st2;

    int cur = s0;
    int end_cur = st1;

    float sm[4]  = {0.f, 0.f, 0.f, 0.f};
    float mxv[4] = {-INFINITY, -INFINITY, -INFINITY, -INFINITY};

    auto flushseg = [&](int s) {
#pragma unroll
        for (int nt = 0; nt < 4; ++nt) {
            sm[nt] += __shfl_xor(sm[nt], 16, 64);
            sm[nt] += __shfl_xor(sm[nt], 32, 64);
            mxv[nt] = fmaxf(mxv[nt], __shfl_xor(mxv[nt], 16, 64));
            mxv[nt] = fmaxf(mxv[nt], __shfl_xor(mxv[nt], 32, 64));
        }
        float S = sm[0], M = mxv[0];
        if (q == 1) { S = sm[1]; M = mxv[1]; }
        if (q == 2) { S = sm[2]; M = mxv[2]; }
        if (q == 3) { S = sm[3]; M = mxv[3]; }
        out[(size_t)s * C + lane] = S + M;
#pragma unroll
        for (int nt = 0; nt < 4; ++nt) { sm[nt] = 0.f; mxv[nt] = -INFINITY; }
    };

    auto loadrows = [&](int pb) -> Rows {
        Rows R = zrows();
        const float* row = inp + (size_t)min(pb + m, N_PTS - 1) * CI;
        if (q == 0) {
            R.r0 = *(const float2*)(row);     R.r1 = *(const float2*)(row + 2);
            R.r2 = *(const float2*)(row + 4); R.r3 = *(const float2*)(row + 6);
        } else if (q == 1) {
            R.r0 = *(const float2*)(row + 8);
        }
        return R;
    };
    auto mkfrag = [&](const Rows& L) -> s16x8 {
        union { s16x8 v; unsigned u[4]; } t;
        t.v = s16x8{0, 0, 0, 0, 0, 0, 0, 0};
        if (q < 2) t.u[0] = pack_trunc(L.r0.x, L.r0.y);
        if (q == 0) {
            t.u[1] = pack_trunc(L.r1.x, L.r1.y);
            t.u[2] = pack_trunc(L.r2.x, L.r2.y);
            t.u[3] = pack_trunc(L.r3.x, L.r3.y);
        }
        return t.v;
    };

    Rows PA = loadrows(start);
    Rows PB = (start + 16 < end_all) ? loadrows(start + 16) : PA;

    for (int base = start; base < end_all; base += 16) {
        Rows L = PA;
        PA = PB;
        if (base + 32 < end_all) PB = loadrows(base + 32);

        const int nb = min(16, end_all - base);

        s16x8 t = mkfrag(L);
        f32x4 xt[4];
#pragma unroll
        for (int nt = 0; nt < 4; ++nt)
            xt[nt] = __builtin_amdgcn_mfma_f32_16x16x32_bf16(t, wfr[nt], zero, 0, 0, 0);

        float xn[4][4];
#pragma unroll
        for (int nt = 0; nt < 4; ++nt)
#pragma unroll
            for (int r = 0; r < 4; ++r) {
                float x = fmaxf(xt[nt][r] + bb[nt], 0.f);
                xn[nt][r] = x;
                float sg = x * d1v[nt];
                float sw = sg * frcp(1.f + __expf(-sg));
                my[(4 * q + r) * LD + nt * 16 + m] = sw;
            }
        lds_fence();

        s16x8 av[2];
#pragma unroll
        for (int kc = 0; kc < 2; ++kc) {
            const float* src = &my[m * LD + kc * 32 + q * 8];
            float4 p0 = *(const float4*)src;
            float4 p1 = *(const float4*)(src + 4);
            union { s16x8 v; unsigned u[4]; } tt;
            tt.u[0] = pack_trunc(p0.x, p0.y);
            tt.u[1] = pack_trunc(p0.z, p0.w);
            tt.u[2] = pack_trunc(p1.x, p1.y);
            tt.u[3] = pack_trunc(p1.z, p1.w);
            av[kc] = tt.v;
        }

        f32x4 xi[4];
#pragma unroll
        for (int nt = 0; nt < 4; ++nt) {
            xi[nt] = __builtin_amdgcn_mfma_f32_16x16x32_bf16(av[0], bfr[nt][0], zero, 0, 0, 0);
            xi[nt] = __builtin_amdgcn_mfma_f32_16x16x32_bf16(av[1], bfr[nt][1], xi[nt], 0, 0, 0);
        }
        // no second fence: per-wave DS pipe is in-order

#pragma unroll
        for (int nt = 0; nt < 4; ++nt)
#pragma unroll
            for (int r = 0; r < 4; ++r) {
                float v   = xi[nt][r] + xgv[nt];
                float wei = frcp(1.f + __expf(-v));
                float x   = xn[nt][r];
                xi[nt][r] = fmaf(x, wei, x);
            }

        const int fin = base + nb;
        if (fin <= end_cur) {
            if (nb == 16) {
#pragma unroll
                for (int nt = 0; nt < 4; ++nt)
#pragma unroll
                    for (int r = 0; r < 4; ++r) {
                        sm[nt] += xi[nt][r];
                        mxv[nt] = fmaxf(mxv[nt], xi[nt][r]);
                    }
            } else {
#pragma unroll
                for (int nt = 0; nt < 4; ++nt)
#pragma unroll
                    for (int r = 0; r < 4; ++r) {
                        bool act = (4 * q + r) < nb;
                        sm[nt] += act ? xi[nt][r] : 0.f;
                        mxv[nt] = fmaxf(mxv[nt], act ? xi[nt][r] : -INFINITY);
                    }
            }
            if (fin == end_cur) { flushseg(cur); ++cur; end_cur = st2; }
        } else {
            const int B = end_cur - base;   // 1..nb-1
#pragma unroll
            for (int nt = 0; nt < 4; ++nt)
#pragma unroll
                for (int r = 0; r < 4; ++r) {
                    bool act = (4 * q + r) < B;
                    sm[nt] += act ? xi[nt][r] : 0.f;
                    mxv[nt] = fmaxf(mxv[nt], act ? xi[nt][r] : -INFINITY);
                }
            flushseg(cur); ++cur;
#pragma unroll
            for (int nt = 0; nt < 4; ++nt)
#pragma unroll
                for (int r = 0; r < 4; ++r) {
                    int pt = 4 * q + r;
                    bool act = (pt >= B) && (pt < nb);
                    sm[nt] += act ? xi[nt][r] : 0.f;
                    mxv[nt] = fmaxf(mxv[nt], act ? xi[nt][r] : -INFINITY);
                }
            end_cur = st2;
        }
    }
}

extern "C" void kernel_launch(void* const* d_in, const int* in_sizes, int n_in,
                              void* d_out, int out_size, void* d_ws, size_t ws_size,
                              hipStream_t stream) {
    const float* inp   = (const float*)d_in[0];
    const int*   unq   = (const int*)d_in[1];
    const float* W     = (const float*)d_in[2];
    const float* gamma = (const float*)d_in[3];
    const float* beta  = (const float*)d_in[4];
    const float* dw1   = (const float*)d_in[5];
    const float* pw1   = (const float*)d_in[6];
    const float* dw2   = (const float*)d_in[7];
    const float* pw2   = (const float*)d_in[8];
    float* out = (float*)d_out;
    float* ws  = (float*)d_ws;
    int* starts = (int*)ws + 1024;

    // no memset: every ws region we read is fully overwritten each launch
    k_moments <<<NBLK_M, 256, 0, stream>>>(inp, unq, ws, starts);
    k_red     <<<65,     256, 0, stream>>>(ws);
    k_gstats  <<<NBLK_G, 256, 0, stream>>>(inp, W, gamma, beta, ws);
    k_prep    <<<1,     1024, 0, stream>>>(W, gamma, beta, dw1, pw1, dw2, pw2, ws);
    k_main    <<<7500,   128, 0, stream>>>(inp, ws, starts, out);
}